// Round 11
// baseline (81.437 us; speedup 1.0000x reference)
//
#include <hip/hip_runtime.h>

// Problem constants (match reference setup_inputs)
constexpr int B_IMG = 8;
constexpr int A_N   = 120000;
constexpr int C_N   = 80;
constexpr int M_N   = 32;

constexpr float ALPHA = 0.25f;

// Fused kernel geometry (R5 champion) + XCD-aware block swizzle
constexpr int BLK  = 256;                          // threads per block (4 waves)
constexpr int APB  = 512;                          // anchors per block
constexpr int NBLK = (A_N + APB - 1) / APB;        // 235 blocks per image
constexpr int NWG  = NBLK * B_IMG;                 // 1880 (divisible by 8!)
constexpr int F4PA = C_N / 4;                      // 20 float4 per anchor
constexpr int U    = 4;                            // float4 per thread per buffer
constexpr int F4_PER_IT = BLK * U;                 // 1024 float4 per iteration
constexpr int NIT  = (APB * F4PA) / F4_PER_IT;     // 10 iterations
constexpr int NXCD = 8;

typedef float f4v __attribute__((ext_vector_type(4)));

// ---------------------------------------------------------------------------
// Helpers
// ---------------------------------------------------------------------------
__device__ __forceinline__ float smooth_l1(float d) {
    d = fabsf(d);
    return (d <= (1.0f / 9.0f)) ? 4.5f * d * d : d - (0.5f / 9.0f);
}

__device__ __forceinline__ float loss_neg(float x) {
    // target == 0: (1-alpha) * p^2 * (-log(1-p))
    float p = fminf(fmaxf(x, 1e-4f), 0.9999f);
    return (1.0f - ALPHA) * p * p * (-__logf(1.0f - p));
}

__device__ __forceinline__ float loss_neg4(f4v v) {
    return loss_neg(v[0]) + loss_neg(v[1]) + loss_neg(v[2]) + loss_neg(v[3]);
}

__device__ __forceinline__ float loss_pos(float x) {
    // target == 1: alpha * (1-p)^2 * (-log(p))
    float p = fminf(fmaxf(x, 1e-4f), 0.9999f);
    float q = 1.0f - p;
    return ALPHA * q * q * (-__logf(p));
}

// Per-anchor assignment: IoU argmax vs 32 gt boxes (1 division), reg loss.
// Returns code: -1 negative (all targets 0), -2 ignore, 0..79 positive class.
__device__ __forceinline__ signed char assign_one(
    const float4 anc, const float* __restrict__ ann,
    const float4* __restrict__ regs, int b, int a,
    float& regl, int& pcount)
{
    const float ax1 = anc.x, ay1 = anc.y, ax2 = anc.z, ay2 = anc.w;
    const float areaA = (ax2 - ax1) * (ay2 - ay1);

    float bi = -1.0f;   // best inter (sentinel loses to any valid box)
    float bu = 1.0f;    // best ua
    int   bm = -1;
    #pragma unroll 2
    for (int m = 0; m < M_N; ++m) {
        const float gx1 = ann[m * 5 + 0];
        const float gy1 = ann[m * 5 + 1];
        const float gx2 = ann[m * 5 + 2];
        const float gy2 = ann[m * 5 + 3];
        const bool valid = (ann[m * 5 + 4] != -1.0f);
        float iw = fminf(ax2, gx2) - fmaxf(ax1, gx1);
        float ih = fminf(ay2, gy2) - fmaxf(ay1, gy1);
        iw = fmaxf(iw, 0.0f);
        ih = fmaxf(ih, 0.0f);
        const float inter = iw * ih;
        const float areaB = (gx2 - gx1) * (gy2 - gy1);
        const float ua = fmaxf(areaA + areaB - inter, 1e-8f);
        // iou_m > iou_best  <=>  inter*bu > bi*ua   (ua,bu > 0)
        const bool better = valid && (inter * bu > bi * ua);
        if (better) { bi = inter; bu = ua; bm = m; }
    }

    const float iouMax = (bm >= 0) ? (bi / bu) : -1.0f;
    const bool positive = (iouMax >= 0.5f);

    if (positive) {
        pcount += 1;
        const float aw  = ax2 - ax1;
        const float ah  = ay2 - ay1;
        const float acx = ax1 + 0.5f * aw;
        const float acy = ay1 + 0.5f * ah;
        const float gx1 = ann[bm * 5 + 0];
        const float gy1 = ann[bm * 5 + 1];
        const float gx2 = ann[bm * 5 + 2];
        const float gy2 = ann[bm * 5 + 3];
        float gw = gx2 - gx1;
        float gh = gy2 - gy1;
        const float gcx = gx1 + 0.5f * gw;
        const float gcy = gy1 + 0.5f * gh;
        gw = fmaxf(gw, 1.0f);
        gh = fmaxf(gh, 1.0f);
        const float t0 = ((gcx - acx) / aw) * 10.0f;  // / 0.1
        const float t1 = ((gcy - acy) / ah) * 10.0f;
        const float t2 = __logf(gw / aw) * 5.0f;      // / 0.2
        const float t3 = __logf(gh / ah) * 5.0f;
        const float4 rg = regs[(size_t)b * A_N + a];
        regl += smooth_l1(t0 - rg.x) + smooth_l1(t1 - rg.y) +
                smooth_l1(t2 - rg.z) + smooth_l1(t3 - rg.w);
    }

    if (iouMax < 0.4f) return -1;
    if (positive)      return (signed char)(int)ann[bm * 5 + 4];
    return -2;
}

// ---------------------------------------------------------------------------
// Fused kernel (R5 structure + XCD swizzle):
//   prefetch iters 0+1 -> phase 1 assignment (LDS code+mask) -> sync
//   -> phase 2 positive corrections -> phase 3 ping-pong masked stream
// Flat 1D grid; bijective swizzle gives each XCD one contiguous image.
// ---------------------------------------------------------------------------
__global__ __launch_bounds__(BLK, 4) void fused_kernel(
    const float* __restrict__ cls,           // [B,A,C]
    const float* __restrict__ regressions,   // [B,A,4]
    const float* __restrict__ anchors,       // [A,4]
    const float* __restrict__ annotations,   // [B,M,5]
    float* __restrict__ clsPart,             // [B*NBLK]
    float* __restrict__ regPart,             // [B*NBLK]
    float* __restrict__ nposPart)            // [B*NBLK]
{
    // XCD-aware bijective swizzle (NWG % 8 == 0): consecutive swz on one XCD
    const int bid = blockIdx.x;
    const int swz = (bid & (NXCD - 1)) * (NWG / NXCD) + (bid >> 3);
    const int b     = swz / NBLK;                      // image
    const int chunk = swz - b * NBLK;                  // chunk within image

    const int base = chunk * APB;                      // first anchor of block
    const int nA   = min(APB, A_N - base);             // anchors in this block
    const float* __restrict__ ann = annotations + (size_t)b * M_N * 5; // uniform
    const float4* __restrict__ regs = (const float4*)regressions;

    __shared__ signed char scode[APB];
    __shared__ float       smask[APB];

    const int t    = threadIdx.x;
    const int wave = t >> 6;
    const int lane = t & 63;
    const bool full = (nA == APB);

    const float* __restrict__ rowbase = cls + (size_t)(b * A_N + base) * C_N;
    const f4v* __restrict__ src = (const f4v*)rowbase;
    // per-wave contiguous segments: idx(it,u) = it*1024 + wave*256 + u*64 + lane
    const f4v* __restrict__ pw = src + wave * (64 * U) + lane;
    const int widx0 = wave * (64 * U) + lane;          // idx at it=0,u=0

    // ---- prefetch iterations 0 and 1 (HBM busy during phase 1) ----
    f4v vA[U], vB[U];
    if (full) {
        #pragma unroll
        for (int u = 0; u < U; ++u) vA[u] = pw[u * 64];
        #pragma unroll
        for (int u = 0; u < U; ++u) vB[u] = pw[F4_PER_IT + u * 64];
    }

    // ---- phase 1: assignment, 2 anchors per thread ----
    float regl = 0.0f;
    int   pcnt = 0;
    #pragma unroll 1
    for (int s = 0; s < APB; s += BLK) {
        const int li = s + t;
        const int a  = base + li;
        signed char c = -2;  // out-of-range / ignore
        if (li < nA) {
            const float4 anc = ((const float4*)anchors)[a];
            c = assign_one(anc, ann, regs, b, a, regl, pcnt);
        }
        scode[li] = c;
        smask[li] = (c != -2) ? 1.0f : 0.0f;
    }
    __syncthreads();

    float csum = 0.0f;

    // ---- phase 2: positive one-hot corrections (rare scalar reads) ----
    #pragma unroll 1
    for (int s = 0; s < APB; s += BLK) {
        const int li = s + t;
        const int code = scode[li];
        if (code >= 0) {
            const float x = rowbase[(size_t)li * C_N + code];
            csum += loss_pos(x) - loss_neg(x);
        }
    }

    // ---- phase 3: ping-pong double-buffered masked stream ----
    if (full) {
        #pragma unroll 1
        for (int it2 = 0; it2 < NIT / 2; ++it2) {
            const int it = it2 * 2;
            float pa = 0.0f;
            #pragma unroll
            for (int u = 0; u < U; ++u) {
                const unsigned idx = (unsigned)(it * F4_PER_IT + widx0 + u * 64);
                pa += smask[idx / 20u] * loss_neg4(vA[u]);
            }
            if (it + 2 < NIT) {
                #pragma unroll
                for (int u = 0; u < U; ++u)
                    vA[u] = pw[(it + 2) * F4_PER_IT + u * 64];
            }
            csum += pa;
            float pb = 0.0f;
            #pragma unroll
            for (int u = 0; u < U; ++u) {
                const unsigned idx = (unsigned)((it + 1) * F4_PER_IT + widx0 + u * 64);
                pb += smask[idx / 20u] * loss_neg4(vB[u]);
            }
            if (it + 3 < NIT) {
                #pragma unroll
                for (int u = 0; u < U; ++u)
                    vB[u] = pw[(it + 3) * F4_PER_IT + u * 64];
            }
            csum += pb;
        }
    } else {
        // tail block: simple masked loop
        const int nF4 = nA * F4PA;
        for (int idx = t; idx < nF4; idx += BLK) {
            const f4v v = src[idx];
            csum += smask[(unsigned)idx / 20u] * loss_neg4(v);
        }
    }

    // ---- block reduce (deterministic, one write per block) ----
    float r = regl, p = (float)pcnt, c = csum;
    #pragma unroll
    for (int off = 32; off; off >>= 1) {
        r += __shfl_down(r, off);
        p += __shfl_down(p, off);
        c += __shfl_down(c, off);
    }
    __shared__ float wr[BLK / 64], wp[BLK / 64], wc[BLK / 64];
    if (lane == 0) { wr[wave] = r; wp[wave] = p; wc[wave] = c; }
    __syncthreads();
    if (t == 0) {
        float rr = 0.0f, pp = 0.0f, cc = 0.0f;
        #pragma unroll
        for (int w = 0; w < BLK / 64; ++w) { rr += wr[w]; pp += wp[w]; cc += wc[w]; }
        const int pidx = b * NBLK + chunk;
        clsPart[pidx]  = cc;
        regPart[pidx]  = rr;
        nposPart[pidx] = pp;
    }
}

// ---------------------------------------------------------------------------
// Finalize: one wave per image, shfl reduce of NBLK partials -> two scalars
// ---------------------------------------------------------------------------
__global__ __launch_bounds__(64 * B_IMG) void finalize_kernel(
    const float* __restrict__ annotations,
    const float* __restrict__ clsPart,
    const float* __restrict__ regPart,
    const float* __restrict__ nposPart,
    float* __restrict__ out)
{
    const int w    = threadIdx.x >> 6;   // image
    const int lane = threadIdx.x & 63;

    float c = 0.0f, r = 0.0f, p = 0.0f;
    for (int i = lane; i < NBLK; i += 64) {
        const int idx = w * NBLK + i;
        c += clsPart[idx];
        r += regPart[idx];
        p += nposPart[idx];
    }
    #pragma unroll
    for (int off = 32; off; off >>= 1) {
        c += __shfl_down(c, off);
        r += __shfl_down(r, off);
        p += __shfl_down(p, off);
    }

    __shared__ float sc[B_IMG], sr[B_IMG];
    if (lane == 0) {
        bool has = false;
        for (int m = 0; m < M_N; ++m)
            has = has || (annotations[(size_t)w * M_N * 5 + m * 5 + 4] != -1.0f);
        const float cl = c / fmaxf(p, 1.0f);
        const float rl = (p > 0.0f) ? r / (p * 4.0f) : 0.0f;
        sc[w] = has ? cl : 0.0f;
        sr[w] = has ? rl : 0.0f;
    }
    __syncthreads();
    if (threadIdx.x == 0) {
        float ca = 0.0f, ra = 0.0f;
        #pragma unroll
        for (int i = 0; i < B_IMG; ++i) { ca += sc[i]; ra += sr[i]; }
        out[0] = ca * (1.0f / B_IMG);
        out[1] = ra * (1.0f / B_IMG);
    }
}

// ---------------------------------------------------------------------------
// Launch
// ---------------------------------------------------------------------------
extern "C" void kernel_launch(void* const* d_in, const int* in_sizes, int n_in,
                              void* d_out, int out_size, void* d_ws, size_t ws_size,
                              hipStream_t stream) {
    const float* classifications = (const float*)d_in[0]; // [B,A,C]
    const float* regressions     = (const float*)d_in[1]; // [B,A,4]
    const float* anchors         = (const float*)d_in[2]; // [1,A,4]
    const float* annotations     = (const float*)d_in[3]; // [B,M,5]
    float* out = (float*)d_out;                           // [2]

    // Workspace: partials written exactly once per call -> no init pass
    float* clsPart  = (float*)d_ws;                        // B*NBLK
    float* regPart  = clsPart + (size_t)B_IMG * NBLK;      // B*NBLK
    float* nposPart = regPart + (size_t)B_IMG * NBLK;      // B*NBLK

    fused_kernel<<<dim3(NWG), BLK, 0, stream>>>(
        classifications, regressions, anchors, annotations,
        clsPart, regPart, nposPart);

    finalize_kernel<<<1, 64 * B_IMG, 0, stream>>>(
        annotations, clsPart, regPart, nposPart, out);
}